// Round 2
// baseline (597.491 us; speedup 1.0000x reference)
//
#include <hip/hip_runtime.h>

#define N_DIM 4
#define A_DIM 512
#define C_DIM 19
#define HW    16384           // 128*128
#define A_PAD 516             // +4 floats to keep 16B row alignment & break bank aliasing

// ---------------------------------------------------------------------------
// Kernel A: per-class sum / sumsq / counts over pixels. One block per (n,a).
// ---------------------------------------------------------------------------
__global__ __launch_bounds__(256) void reduce_kernel(const float* __restrict__ feat,
                                                     const int*   __restrict__ labels,
                                                     float* __restrict__ gsum,
                                                     float* __restrict__ gsq,
                                                     float* __restrict__ gcnt) {
    const int b = blockIdx.x;
    const int n = b >> 9;        // / A_DIM
    const int a = b & (A_DIM - 1);
    const float4* f4 = (const float4*)(feat + ((size_t)(n * A_DIM + a)) * HW);
    const int4*   l4 = (const int4*)(labels + n * HW);

    __shared__ float s_sum[4][20];
    __shared__ float s_sq[4][20];
    __shared__ float s_cnt[4][20];

    const int tid = threadIdx.x;
    const int w = tid >> 6;
    if (tid < 80) {
        ((float*)s_sum)[tid] = 0.f;
        ((float*)s_sq)[tid]  = 0.f;
        ((float*)s_cnt)[tid] = 0.f;
    }
    __syncthreads();

    const bool do_cnt = (a == 0);
    for (int i = tid; i < HW / 4; i += 256) {
        float4 f = f4[i];
        int4   lb = l4[i];
        if ((unsigned)lb.x < C_DIM) {
            atomicAdd(&s_sum[w][lb.x], f.x);
            atomicAdd(&s_sq[w][lb.x], f.x * f.x);
            if (do_cnt) atomicAdd(&s_cnt[w][lb.x], 1.f);
        }
        if ((unsigned)lb.y < C_DIM) {
            atomicAdd(&s_sum[w][lb.y], f.y);
            atomicAdd(&s_sq[w][lb.y], f.y * f.y);
            if (do_cnt) atomicAdd(&s_cnt[w][lb.y], 1.f);
        }
        if ((unsigned)lb.z < C_DIM) {
            atomicAdd(&s_sum[w][lb.z], f.z);
            atomicAdd(&s_sq[w][lb.z], f.z * f.z);
            if (do_cnt) atomicAdd(&s_cnt[w][lb.z], 1.f);
        }
        if ((unsigned)lb.w < C_DIM) {
            atomicAdd(&s_sum[w][lb.w], f.w);
            atomicAdd(&s_sq[w][lb.w], f.w * f.w);
            if (do_cnt) atomicAdd(&s_cnt[w][lb.w], 1.f);
        }
    }
    __syncthreads();

    if (tid < C_DIM) {
        float ss = s_sum[0][tid] + s_sum[1][tid] + s_sum[2][tid] + s_sum[3][tid];
        float sq = s_sq[0][tid] + s_sq[1][tid] + s_sq[2][tid] + s_sq[3][tid];
        atomicAdd(&gsum[tid * A_DIM + a], ss);
        atomicAdd(&gsq[tid * A_DIM + a], sq);
        if (do_cnt) {
            float cn = s_cnt[0][tid] + s_cnt[1][tid] + s_cnt[2][tid] + s_cnt[3][tid];
            atomicAdd(&gcnt[tid], cn);
        }
    }
}

// ---------------------------------------------------------------------------
// Kernel B: finalize cov_new (full update_CV formula) + build S[k][c] table.
// Single block, 512 threads.
// ---------------------------------------------------------------------------
__global__ __launch_bounds__(512) void finalize_kernel(const float* __restrict__ gsum,
                                                       const float* __restrict__ gsq,
                                                       const float* __restrict__ gcnt,
                                                       const float* __restrict__ CoV,
                                                       const float* __restrict__ Ave,
                                                       const float* __restrict__ Amount,
                                                       const float* __restrict__ weight,
                                                       const float* __restrict__ ratio_p,
                                                       float* __restrict__ S) {
    alignas(16) __shared__ float s_cov[C_DIM][A_PAD];
    alignas(16) __shared__ float s_w[C_DIM][A_PAD];
    __shared__ float s_wcv[C_DIM];
    __shared__ float s_inv[C_DIM];

    const int tid = threadIdx.x;
    if (tid < C_DIM) {
        float cnt = gcnt[tid];
        float cs  = (cnt == 0.f) ? 1.f : cnt;
        float denom = cnt + Amount[tid];
        s_wcv[tid] = (denom == 0.f) ? 0.f : cnt / denom;
        s_inv[tid] = 1.f / cs;
    }
    __syncthreads();

    for (int idx = tid; idx < C_DIM * A_DIM; idx += 512) {
        const int c = idx >> 9;          // / A_DIM
        const int a = idx & (A_DIM - 1);
        float inv = s_inv[c];
        float sm  = gsum[idx];
        float ave = sm * inv;
        float var = (gsq[idx] - sm * ave) * inv;
        float wcv = s_wcv[c];
        float d   = Ave[idx] - ave;
        float cov = CoV[idx] * (1.f - wcv) + var * wcv + wcv * (1.f - wcv) * d * d;
        s_cov[c][a] = cov;
        s_w[c][a]   = weight[idx];
    }
    __syncthreads();

    const float ratio = *ratio_p;
    for (int e = tid; e < C_DIM * C_DIM; e += 512) {
        const int k = e / C_DIM;
        const int c = e % C_DIM;
        const float4* cv4 = (const float4*)&s_cov[k][0];
        const float4* wc4 = (const float4*)&s_w[c][0];
        const float4* wk4 = (const float4*)&s_w[k][0];
        float acc = 0.f;
        for (int a4 = 0; a4 < A_DIM / 4; ++a4) {
            float4 cv = cv4[a4];
            float4 wc = wc4[a4];
            float4 wk = wk4[a4];
            float dx = wc.x - wk.x, dy = wc.y - wk.y;
            float dz = wc.z - wk.z, dw = wc.w - wk.w;
            acc += cv.x * dx * dx + cv.y * dy * dy + cv.z * dz * dz + cv.w * dw * dw;
        }
        S[e] = ratio * acc;
    }
}

// ---------------------------------------------------------------------------
// Kernel C: out[n,c,h,w] = y[n,c,h,w] + 0.5 * S[label(n,h,w)][c]  (valid mask)
// 1024 contiguous elements per block => uniform (n,c) per block.
// ---------------------------------------------------------------------------
__global__ __launch_bounds__(256) void apply_kernel(const float* __restrict__ y,
                                                    const int*   __restrict__ labels,
                                                    const float* __restrict__ S,
                                                    float* __restrict__ out) {
    __shared__ float s_S[C_DIM * C_DIM];
    const int tid = threadIdx.x;
    for (int i = tid; i < C_DIM * C_DIM; i += 256) s_S[i] = S[i];
    __syncthreads();

    const int g = blockIdx.x * 256 + tid;             // float4 index
    const int per_n = C_DIM * (HW / 4);               // 77824
    const int n = g / per_n;
    const int rem = g - n * per_n;
    const int c = rem >> 12;                          // / 4096
    const int hw4 = rem & 4095;

    float4 yv = ((const float4*)y)[g];
    int4 lb = ((const int4*)(labels + n * HW))[hw4];
    float4 r;
    {
        int l = lb.x; bool v = (l != 255); l = ((unsigned)l < C_DIM) ? l : 0;
        r.x = yv.x + (v ? 0.5f * s_S[l * C_DIM + c] : 0.f);
    }
    {
        int l = lb.y; bool v = (l != 255); l = ((unsigned)l < C_DIM) ? l : 0;
        r.y = yv.y + (v ? 0.5f * s_S[l * C_DIM + c] : 0.f);
    }
    {
        int l = lb.z; bool v = (l != 255); l = ((unsigned)l < C_DIM) ? l : 0;
        r.z = yv.z + (v ? 0.5f * s_S[l * C_DIM + c] : 0.f);
    }
    {
        int l = lb.w; bool v = (l != 255); l = ((unsigned)l < C_DIM) ? l : 0;
        r.w = yv.w + (v ? 0.5f * s_S[l * C_DIM + c] : 0.f);
    }
    ((float4*)out)[g] = r;
}

// ---------------------------------------------------------------------------
extern "C" void kernel_launch(void* const* d_in, const int* in_sizes, int n_in,
                              void* d_out, int out_size, void* d_ws, size_t ws_size,
                              hipStream_t stream) {
    const float* feat   = (const float*)d_in[0];   // [N,A,H,W]
    const float* y      = (const float*)d_in[1];   // [N,C,H,W]
    const int*   labels = (const int*)d_in[2];     // [N,1,H,W] int32
    const float* weight = (const float*)d_in[3];   // [C,A]
    const float* CoV    = (const float*)d_in[4];   // [C,A]
    const float* Ave    = (const float*)d_in[5];   // [C,A]
    const float* Amount = (const float*)d_in[6];   // [C]
    const float* ratio  = (const float*)d_in[7];   // scalar

    float* out  = (float*)d_out;
    float* ws   = (float*)d_ws;
    float* gsum = ws;                               // C*A
    float* gsq  = ws + C_DIM * A_DIM;               // C*A
    float* gcnt = ws + 2 * C_DIM * A_DIM;           // C (padded to 32)
    float* S    = gcnt + 32;                        // C*C

    const size_t zero_bytes = (size_t)(2 * C_DIM * A_DIM + 32 + C_DIM * C_DIM) * sizeof(float);
    hipMemsetAsync(d_ws, 0, zero_bytes, stream);

    reduce_kernel<<<N_DIM * A_DIM, 256, 0, stream>>>(feat, labels, gsum, gsq, gcnt);
    finalize_kernel<<<1, 512, 0, stream>>>(gsum, gsq, gcnt, CoV, Ave, Amount, weight, ratio, S);
    apply_kernel<<<(N_DIM * C_DIM * (HW / 4)) / 256, 256, 0, stream>>>(y, labels, S, out);
}

// Round 3
// 269.626 us; speedup vs baseline: 2.2160x; 2.2160x over previous
//
#include <hip/hip_runtime.h>

#define N_DIM 4
#define A_DIM 512
#define C_DIM 19
#define HW    16384           // 128*128
#define A_PAD 516             // +4 floats to keep 16B row alignment & break bank aliasing

// ---------------------------------------------------------------------------
// Kernel A: per-class sum / sumsq over pixels. One block per (n,a).
// Register select-accumulate (NO LDS atomics — that was the 427us bottleneck).
// ---------------------------------------------------------------------------
__global__ __launch_bounds__(256) void reduce_kernel(const float* __restrict__ feat,
                                                     const int*   __restrict__ labels,
                                                     float* __restrict__ gsum,
                                                     float* __restrict__ gsq) {
    const int b = blockIdx.x;
    const int n = b >> 9;        // / A_DIM
    const int a = b & (A_DIM - 1);
    const float4* f4 = (const float4*)(feat + ((size_t)(n * A_DIM + a)) * HW);
    const int4*   l4 = (const int4*)(labels + n * HW);

    const int tid = threadIdx.x;

    float s[C_DIM];
    float q[C_DIM];
    #pragma unroll
    for (int c = 0; c < C_DIM; ++c) { s[c] = 0.f; q[c] = 0.f; }

    #pragma unroll 2
    for (int i = tid; i < HW / 4; i += 256) {
        float4 f = f4[i];
        int4   lb = l4[i];
        #pragma unroll
        for (int c = 0; c < C_DIM; ++c) {
            float sx = (lb.x == c) ? f.x : 0.f;
            float sy = (lb.y == c) ? f.y : 0.f;
            float sz = (lb.z == c) ? f.z : 0.f;
            float sw = (lb.w == c) ? f.w : 0.f;
            s[c] += sx + sy + sz + sw;
            q[c] = fmaf(sx, f.x, q[c]);
            q[c] = fmaf(sy, f.y, q[c]);
            q[c] = fmaf(sz, f.z, q[c]);
            q[c] = fmaf(sw, f.w, q[c]);
        }
    }

    // wave butterfly reduction (64 lanes), then one atomic per wave per class
    #pragma unroll
    for (int c = 0; c < C_DIM; ++c) {
        #pragma unroll
        for (int off = 32; off >= 1; off >>= 1) {
            s[c] += __shfl_xor(s[c], off);
            q[c] += __shfl_xor(q[c], off);
        }
    }
    if ((tid & 63) == 0) {
        #pragma unroll
        for (int c = 0; c < C_DIM; ++c) {
            atomicAdd(&gsum[c * A_DIM + a], s[c]);
            atomicAdd(&gsq[c * A_DIM + a], q[c]);
        }
    }
}

// ---------------------------------------------------------------------------
// Kernel A2: label counts. One block per n (tiny; off critical path).
// ---------------------------------------------------------------------------
__global__ __launch_bounds__(256) void count_kernel(const int* __restrict__ labels,
                                                    float* __restrict__ gcnt) {
    __shared__ float s_cnt[4][20];
    const int tid = threadIdx.x;
    const int w = tid >> 6;
    if (tid < 80) ((float*)s_cnt)[tid] = 0.f;
    __syncthreads();
    const int4* l4 = (const int4*)(labels + blockIdx.x * HW);
    for (int i = tid; i < HW / 4; i += 256) {
        int4 lb = l4[i];
        if ((unsigned)lb.x < C_DIM) atomicAdd(&s_cnt[w][lb.x], 1.f);
        if ((unsigned)lb.y < C_DIM) atomicAdd(&s_cnt[w][lb.y], 1.f);
        if ((unsigned)lb.z < C_DIM) atomicAdd(&s_cnt[w][lb.z], 1.f);
        if ((unsigned)lb.w < C_DIM) atomicAdd(&s_cnt[w][lb.w], 1.f);
    }
    __syncthreads();
    if (tid < C_DIM) {
        float cn = s_cnt[0][tid] + s_cnt[1][tid] + s_cnt[2][tid] + s_cnt[3][tid];
        atomicAdd(&gcnt[tid], cn);
    }
}

// ---------------------------------------------------------------------------
// Kernel B: finalize cov_new (full update_CV formula) + build S[k][c] table.
// ---------------------------------------------------------------------------
__global__ __launch_bounds__(512) void finalize_kernel(const float* __restrict__ gsum,
                                                       const float* __restrict__ gsq,
                                                       const float* __restrict__ gcnt,
                                                       const float* __restrict__ CoV,
                                                       const float* __restrict__ Ave,
                                                       const float* __restrict__ Amount,
                                                       const float* __restrict__ weight,
                                                       const float* __restrict__ ratio_p,
                                                       float* __restrict__ S) {
    alignas(16) __shared__ float s_cov[C_DIM][A_PAD];
    alignas(16) __shared__ float s_w[C_DIM][A_PAD];
    __shared__ float s_wcv[C_DIM];
    __shared__ float s_inv[C_DIM];

    const int tid = threadIdx.x;
    if (tid < C_DIM) {
        float cnt = gcnt[tid];
        float cs  = (cnt == 0.f) ? 1.f : cnt;
        float denom = cnt + Amount[tid];
        s_wcv[tid] = (denom == 0.f) ? 0.f : cnt / denom;
        s_inv[tid] = 1.f / cs;
    }
    __syncthreads();

    for (int idx = tid; idx < C_DIM * A_DIM; idx += 512) {
        const int c = idx >> 9;          // / A_DIM
        const int a = idx & (A_DIM - 1);
        float inv = s_inv[c];
        float sm  = gsum[idx];
        float ave = sm * inv;
        float var = (gsq[idx] - sm * ave) * inv;
        float wcv = s_wcv[c];
        float d   = Ave[idx] - ave;
        float cov = CoV[idx] * (1.f - wcv) + var * wcv + wcv * (1.f - wcv) * d * d;
        s_cov[c][a] = cov;
        s_w[c][a]   = weight[idx];
    }
    __syncthreads();

    const float ratio = *ratio_p;
    for (int e = tid; e < C_DIM * C_DIM; e += 512) {
        const int k = e / C_DIM;
        const int c = e % C_DIM;
        const float4* cv4 = (const float4*)&s_cov[k][0];
        const float4* wc4 = (const float4*)&s_w[c][0];
        const float4* wk4 = (const float4*)&s_w[k][0];
        float acc = 0.f;
        for (int a4 = 0; a4 < A_DIM / 4; ++a4) {
            float4 cv = cv4[a4];
            float4 wc = wc4[a4];
            float4 wk = wk4[a4];
            float dx = wc.x - wk.x, dy = wc.y - wk.y;
            float dz = wc.z - wk.z, dw = wc.w - wk.w;
            acc += cv.x * dx * dx + cv.y * dy * dy + cv.z * dz * dz + cv.w * dw * dw;
        }
        S[e] = ratio * acc;
    }
}

// ---------------------------------------------------------------------------
// Kernel C: out[n,c,h,w] = y[n,c,h,w] + 0.5 * S[label(n,h,w)][c]  (valid mask)
// ---------------------------------------------------------------------------
__global__ __launch_bounds__(256) void apply_kernel(const float* __restrict__ y,
                                                    const int*   __restrict__ labels,
                                                    const float* __restrict__ S,
                                                    float* __restrict__ out) {
    __shared__ float s_S[C_DIM * C_DIM];
    const int tid = threadIdx.x;
    for (int i = tid; i < C_DIM * C_DIM; i += 256) s_S[i] = S[i];
    __syncthreads();

    const int g = blockIdx.x * 256 + tid;             // float4 index
    const int per_n = C_DIM * (HW / 4);               // 77824
    const int n = g / per_n;
    const int rem = g - n * per_n;
    const int c = rem >> 12;                          // / 4096
    const int hw4 = rem & 4095;

    float4 yv = ((const float4*)y)[g];
    int4 lb = ((const int4*)(labels + n * HW))[hw4];
    float4 r;
    {
        int l = lb.x; bool v = (l != 255); l = ((unsigned)l < C_DIM) ? l : 0;
        r.x = yv.x + (v ? 0.5f * s_S[l * C_DIM + c] : 0.f);
    }
    {
        int l = lb.y; bool v = (l != 255); l = ((unsigned)l < C_DIM) ? l : 0;
        r.y = yv.y + (v ? 0.5f * s_S[l * C_DIM + c] : 0.f);
    }
    {
        int l = lb.z; bool v = (l != 255); l = ((unsigned)l < C_DIM) ? l : 0;
        r.z = yv.z + (v ? 0.5f * s_S[l * C_DIM + c] : 0.f);
    }
    {
        int l = lb.w; bool v = (l != 255); l = ((unsigned)l < C_DIM) ? l : 0;
        r.w = yv.w + (v ? 0.5f * s_S[l * C_DIM + c] : 0.f);
    }
    ((float4*)out)[g] = r;
}

// ---------------------------------------------------------------------------
extern "C" void kernel_launch(void* const* d_in, const int* in_sizes, int n_in,
                              void* d_out, int out_size, void* d_ws, size_t ws_size,
                              hipStream_t stream) {
    const float* feat   = (const float*)d_in[0];   // [N,A,H,W]
    const float* y      = (const float*)d_in[1];   // [N,C,H,W]
    const int*   labels = (const int*)d_in[2];     // [N,1,H,W] int32
    const float* weight = (const float*)d_in[3];   // [C,A]
    const float* CoV    = (const float*)d_in[4];   // [C,A]
    const float* Ave    = (const float*)d_in[5];   // [C,A]
    const float* Amount = (const float*)d_in[6];   // [C]
    const float* ratio  = (const float*)d_in[7];   // scalar

    float* out  = (float*)d_out;
    float* ws   = (float*)d_ws;
    float* gsum = ws;                               // C*A
    float* gsq  = ws + C_DIM * A_DIM;               // C*A
    float* gcnt = ws + 2 * C_DIM * A_DIM;           // C (padded to 32)
    float* S    = gcnt + 32;                        // C*C

    const size_t zero_bytes = (size_t)(2 * C_DIM * A_DIM + 32 + C_DIM * C_DIM) * sizeof(float);
    hipMemsetAsync(d_ws, 0, zero_bytes, stream);

    count_kernel<<<N_DIM, 256, 0, stream>>>(labels, gcnt);
    reduce_kernel<<<N_DIM * A_DIM, 256, 0, stream>>>(feat, labels, gsum, gsq);
    finalize_kernel<<<1, 512, 0, stream>>>(gsum, gsq, gcnt, CoV, Ave, Amount, weight, ratio, S);
    apply_kernel<<<(N_DIM * C_DIM * (HW / 4)) / 256, 256, 0, stream>>>(y, labels, S, out);
}